// Round 2
// baseline (46.976 us; speedup 1.0000x reference)
//
#include <hip/hip_runtime.h>

#define M_ROWS 65536
#define LENGTH 512
#define BLOCK 256
// each wave handles 1024 consecutive floats (= 2 rows); 4 waves/block
// total waves = 65536*512/1024 = 32768 -> 8192 blocks
#define NBLOCKS 8192

__device__ __forceinline__ void chunk_acc(float& acc, float4 v, float4 m, float p0) {
  float t;
  t = fabsf(v.x - p0) - 1.0f;  acc += fmaxf(t, 0.0f) * m.x;
  t = fabsf(v.y - v.x) - 1.0f; acc += fmaxf(t, 0.0f) * m.y;
  t = fabsf(v.z - v.y) - 1.0f; acc += fmaxf(t, 0.0f) * m.z;
  t = fabsf(v.w - v.z) - 1.0f; acc += fmaxf(t, 0.0f) * m.w;
}

__global__ __launch_bounds__(BLOCK) void connect_loss_partial(
    const float* __restrict__ x,
    const float* __restrict__ mask,
    float* __restrict__ part) {
  const int lane = threadIdx.x & 63;
  const int wave = threadIdx.x >> 6;
  const size_t wave_base = ((size_t)blockIdx.x * (BLOCK / 64) + wave) * 1024;

  const float4* xb = reinterpret_cast<const float4*>(x + wave_base);
  const float4* mb = reinterpret_cast<const float4*>(mask + wave_base);

  // Issue all 8 coalesced 1KB wave-loads up front (max MLP, single wait).
  float4 v0 = xb[lane];
  float4 v1 = xb[64 + lane];
  float4 v2 = xb[128 + lane];
  float4 v3 = xb[192 + lane];
  float4 m0 = mb[lane];
  float4 m1 = mb[64 + lane];
  float4 m2 = mb[128 + lane];
  float4 m3 = mb[192 + lane];

  float acc = 0.0f;

  // chunk 0: covers row floats [0,256); lane 0 is column 0 -> zero first diff
  {
    float p = __shfl_up(v0.w, 1);
    if (lane == 0) p = v0.x;
    chunk_acc(acc, v0, m0, p);
  }
  // chunk 1: floats [256,512); lane 0's prev is chunk0 lane63 .w
  {
    float p = __shfl_up(v1.w, 1);
    float last = __shfl(v0.w, 63);
    if (lane == 0) p = last;
    chunk_acc(acc, v1, m1, p);
  }
  // chunk 2: floats [512,768) = start of row 2; lane 0 is column 0 -> zero diff
  {
    float p = __shfl_up(v2.w, 1);
    if (lane == 0) p = v2.x;
    chunk_acc(acc, v2, m2, p);
  }
  // chunk 3: floats [768,1024); lane 0's prev is chunk2 lane63 .w
  {
    float p = __shfl_up(v3.w, 1);
    float last = __shfl(v2.w, 63);
    if (lane == 0) p = last;
    chunk_acc(acc, v3, m3, p);
  }

  // wave reduction (64 lanes)
#pragma unroll
  for (int off = 32; off; off >>= 1) acc += __shfl_down(acc, off);

  __shared__ float s[BLOCK / 64];
  if (lane == 0) s[wave] = acc;
  __syncthreads();
  if (threadIdx.x == 0) part[blockIdx.x] = s[0] + s[1] + s[2] + s[3];
}

__global__ __launch_bounds__(BLOCK) void connect_loss_reduce(
    const float* __restrict__ part, float* __restrict__ out, int n) {
  const int wave = threadIdx.x >> 6;
  const int lane = threadIdx.x & 63;
  float acc = 0.0f;
  const float4* p4 = reinterpret_cast<const float4*>(part);
  for (int i = threadIdx.x; i < n / 4; i += BLOCK) {
    float4 v = p4[i];
    acc += (v.x + v.y) + (v.z + v.w);
  }
#pragma unroll
  for (int off = 32; off; off >>= 1) acc += __shfl_down(acc, off);
  __shared__ float s[BLOCK / 64];
  if (lane == 0) s[wave] = acc;
  __syncthreads();
  if (threadIdx.x == 0) out[0] = s[0] + s[1] + s[2] + s[3];
}

extern "C" void kernel_launch(void* const* d_in, const int* in_sizes, int n_in,
                              void* d_out, int out_size, void* d_ws, size_t ws_size,
                              hipStream_t stream) {
  const float* x = (const float*)d_in[0];
  const float* mask = (const float*)d_in[1];
  float* out = (float*)d_out;
  float* part = (float*)d_ws;  // NBLOCKS floats

  connect_loss_partial<<<NBLOCKS, BLOCK, 0, stream>>>(x, mask, part);
  connect_loss_reduce<<<1, BLOCK, 0, stream>>>(part, out, NBLOCKS);
}